// Round 5
// baseline (1370.830 us; speedup 1.0000x reference)
//
#include <hip/hip_runtime.h>
#include <stdint.h>
#include <math.h>

// Problem constants
#define B_DIM 64
#define E_DIM 512
#define H_DIM 1024
#define V_DIM 32000
#define T_STEPS 31
#define GATES 4096          // 4*H
#define OUT_COLS 62         // 2*T
#define NCHUNK 125          // 32000 / 256
#define STOT 32             // K=1024 -> 32 k-steps of 32
#define NTPAIR 16           // ceil(31/2) t-pairs
#define NBLK2 (NTPAIR * NCHUNK)  // 2000 fused-logits blocks (= 8 * 250)

// JAX >= 0.4.36 default: jax_threefry_partitionable = True
#define RNG_PARTITIONABLE 1

typedef _Float16 half8 __attribute__((ext_vector_type(8)));
typedef float floatx4 __attribute__((ext_vector_type(4)));

// ---------------- threefry2x32 (exact JAX reference) ----------------
__device__ __forceinline__ void tf_round(uint32_t& x0, uint32_t& x1, int r) {
  x0 += x1;
  x1 = (x1 << r) | (x1 >> (32 - r));
  x1 ^= x0;
}

__device__ __forceinline__ void threefry2x32(uint32_t k0, uint32_t k1,
                                             uint32_t& x0, uint32_t& x1) {
  uint32_t k2 = k0 ^ k1 ^ 0x1BD11BDAu;
  x0 += k0; x1 += k1;
  tf_round(x0,x1,13); tf_round(x0,x1,15); tf_round(x0,x1,26); tf_round(x0,x1,6);
  x0 += k1; x1 += k2 + 1u;
  tf_round(x0,x1,17); tf_round(x0,x1,29); tf_round(x0,x1,16); tf_round(x0,x1,24);
  x0 += k2; x1 += k0 + 2u;
  tf_round(x0,x1,13); tf_round(x0,x1,15); tf_round(x0,x1,26); tf_round(x0,x1,6);
  x0 += k0; x1 += k1 + 3u;
  tf_round(x0,x1,17); tf_round(x0,x1,29); tf_round(x0,x1,16); tf_round(x0,x1,24);
  x0 += k1; x1 += k2 + 4u;
  tf_round(x0,x1,13); tf_round(x0,x1,15); tf_round(x0,x1,26); tf_round(x0,x1,6);
  x0 += k2; x1 += k0 + 5u;
}

// ---------------- small utility kernels ----------------
__global__ void zero_kernel(float* __restrict__ o, int n) {
  int i = blockIdx.x * blockDim.x + threadIdx.x;
  if (i < n) o[i] = 0.0f;
}

__global__ void copy_kernel(const float* __restrict__ a, float* __restrict__ o, int n) {
  int i = blockIdx.x * blockDim.x + threadIdx.x;
  if (i < n) o[i] = a[i];
}

// ---------------- weight repack: fp32 (a [+ b]) -> f16 hi/lo MFMA B-fragments ----
__global__ __launch_bounds__(256)
void repack_w(const float* __restrict__ Wa, const float* __restrict__ Wb,
              _Float16* __restrict__ pk, int N) {
  int gw = blockIdx.x * 4 + (threadIdx.x >> 6);
  int total = (N >> 4) * STOT;
  if (gw >= total) return;
  int nt = gw >> 5, s = gw & 31;
  int lane = threadIdx.x & 63;
  int quad = lane >> 4, lm = lane & 15;
  int col = nt * 16 + lm;
  half8 hi, lo;
#pragma unroll
  for (int j = 0; j < 8; ++j) {
    int row = s * 32 + quad * 8 + j;
    float v = Wa[(size_t)row * N + col];
    if (Wb) v += Wb[(size_t)row * N + col];
    _Float16 h = (_Float16)v;
    hi[j] = h;
    lo[j] = (_Float16)(v - (float)h);
  }
  _Float16* o = pk + ((size_t)(nt * 32 + s) * 2) * 512 + lane * 8;
  *(half8*)o = hi;
  *(half8*)(o + 512) = lo;
}

// Fragment-load / MFMA macros (register A+B path, logits kernel).
#define LOAD_FRAGS(s_, A_, B_)                                              \
  {                                                                         \
    _Pragma("unroll")                                                       \
    for (int mt = 0; mt < 4; ++mt) {                                        \
      const half8* ap = Apk + ((size_t)(mt * 32 + (s_)) * 2) * 64 + lane;   \
      A_[mt][0] = ap[0];                                                    \
      A_[mt][1] = ap[64];                                                   \
    }                                                                       \
    _Pragma("unroll")                                                       \
    for (int nt = 0; nt < 4; ++nt) {                                        \
      const half8* bp =                                                     \
          Wpk + ((size_t)((nt0 + nt) * 32 + (s_)) * 2) * 64 + lane;         \
      B_[nt][0] = bp[0];                                                    \
      B_[nt][1] = bp[64];                                                   \
    }                                                                       \
  }

#define DO_MFMA(A_, B_)                                                     \
  {                                                                         \
    _Pragma("unroll")                                                       \
    for (int mt = 0; mt < 4; ++mt) {                                        \
      _Pragma("unroll")                                                     \
      for (int nt = 0; nt < 4; ++nt) {                                      \
        acc[mt][nt] = __builtin_amdgcn_mfma_f32_16x16x32_f16(               \
            A_[mt][0], B_[nt][0], acc[mt][nt], 0, 0, 0);                    \
        acc[mt][nt] = __builtin_amdgcn_mfma_f32_16x16x32_f16(               \
            A_[mt][1], B_[nt][0], acc[mt][nt], 0, 0, 0);                    \
        acc[mt][nt] = __builtin_amdgcn_mfma_f32_16x16x32_f16(               \
            A_[mt][0], B_[nt][1], acc[mt][nt], 0, 0, 0);                    \
      }                                                                     \
    }                                                                       \
  }

// ---------------- fused LSTM decode step ----------------
// One launch per step (replaces mfma_gemm + gates_kernel + 8 MB z round-trip).
// Grid (64, 2) x 512 threads. Block (x, mhalf): h-cols x*16..x*16+15, batch
// rows mhalf*32..+31. The 4 gate quadrants for those cols (z-cols x*16+q*1024)
// are computed in-block over full K=1024 (no k-split), s-split 2-way per
// quadrant, partials summed in LDS. Gates + A-fragment pack fused; z never
// touches global. W2 slices hit the same blocks each launch -> L2-resident.
__global__ __launch_bounds__(512, 2)
void lstm_step_fused(const half8* __restrict__ Apk,    // hpk slot t
                     const half8* __restrict__ Wpk,    // W2_pk
                     const float* __restrict__ bias,   // b2
                     float* __restrict__ c,            // state (in/out)
                     float* __restrict__ h_out,        // h f32 (final copy)
                     _Float16* __restrict__ hpk_next)  // hpk slot t+1
{
  const int x = blockIdx.x;        // h-col group (16 cols)
  const int mhalf = blockIdx.y;    // batch half (32 rows)
  const int tid = threadIdx.x;
  const int wv = tid >> 6;         // 0..7
  const int quad = wv >> 1;        // gate quadrant 0..3
  const int spart = wv & 1;        // K-split half
  const int lane = tid & 63;

  __shared__ float zsm[32][68];    // [local batch row][quad*16 + col]

  for (int i = tid; i < 32 * 68; i += 512) ((float*)zsm)[i] = 0.0f;
  __syncthreads();

  // ---- GEMM: 2 mt tiles x 1 nt tile, s in [spart*16, +16) ----
  const int nt = quad * 64 + x;
  floatx4 acc[2] = {};
  half8 a0[2][2], b0[2], a1[2][2], b1[2];

#define LF2(s_, A_, B_)                                                        \
  {                                                                            \
    _Pragma("unroll")                                                          \
    for (int i = 0; i < 2; ++i) {                                              \
      const half8* ap =                                                        \
          Apk + ((size_t)((mhalf * 2 + i) * 32 + (s_)) * 2) * 64 + lane;       \
      A_[i][0] = ap[0];                                                        \
      A_[i][1] = ap[64];                                                       \
    }                                                                          \
    const half8* bp = Wpk + ((size_t)(nt * 32 + (s_)) * 2) * 64 + lane;        \
    B_[0] = bp[0];                                                             \
    B_[1] = bp[64];                                                            \
  }

#define MM2(A_, B_)                                                            \
  {                                                                            \
    _Pragma("unroll")                                                          \
    for (int i = 0; i < 2; ++i) {                                              \
      acc[i] = __builtin_amdgcn_mfma_f32_16x16x32_f16(A_[i][0], B_[0],         \
                                                      acc[i], 0, 0, 0);        \
      acc[i] = __builtin_amdgcn_mfma_f32_16x16x32_f16(A_[i][1], B_[0],         \
                                                      acc[i], 0, 0, 0);        \
      acc[i] = __builtin_amdgcn_mfma_f32_16x16x32_f16(A_[i][0], B_[1],         \
                                                      acc[i], 0, 0, 0);        \
    }                                                                          \
  }

  const int s0 = spart * 16;
  LF2(s0, a0, b0);
  for (int s = s0; s < s0 + 16; s += 2) {
    LF2(s + 1, a1, b1);
    MM2(a0, b0);
    if (s + 2 < s0 + 16) LF2(s + 2, a0, b0);
    MM2(a1, b1);
  }
#undef LF2
#undef MM2

  // C layout: col = lane&15, row = (lane>>4)*4 + r; local row = i*16 + ...
  const int cm = lane & 15, rq = lane >> 4;
#pragma unroll
  for (int i = 0; i < 2; ++i)
#pragma unroll
    for (int r = 0; r < 4; ++r)
      atomicAdd(&zsm[i * 16 + rq * 4 + r][quad * 16 + cm], acc[i][r]);
  __syncthreads();

  // ---- gates + pack: thread = (local batch row, h-col) ----
  const int bl = tid >> 4;               // 0..31
  const int b = mhalf * 32 + bl;         // global batch row
  const int hl = tid & 15;
  const int j = x * 16 + hl;             // h-col

  float zi = bias[j]        + zsm[bl][hl];
  float zf = bias[j + 1024] + zsm[bl][16 + hl];
  float zg = bias[j + 2048] + zsm[bl][32 + hl];
  float zo = bias[j + 3072] + zsm[bl][48 + hl];

  float cp = c[(size_t)b * H_DIM + j];
  float si = 1.0f / (1.0f + expf(-zi));
  float sf = 1.0f / (1.0f + expf(-zf));
  float so = 1.0f / (1.0f + expf(-zo));
  float cn = sf * cp + si * zg;
  c[(size_t)b * H_DIM + j] = cn;
  float hv = so * cn;
  h_out[(size_t)b * H_DIM + j] = hv;

  // pack into MFMA A-fragment hi/lo layout (same formula as gates_kernel)
  int mt = b >> 4, lm = b & 15;
  int s = j >> 5, q2 = (j >> 3) & 3, jj = j & 7;
  size_t off = ((size_t)(mt * 32 + s) * 2) * 512 + (size_t)(q2 * 16 + lm) * 8 + jj;
  _Float16 hh = (_Float16)hv;
  hpk_next[off] = hh;
  hpk_next[off + 512] = (_Float16)(hv - (float)hh);
}

// ---------------- fused logits GEMM + sampling stage 1 ----------------
// (byte-identical to the verified round-4 version)
__global__ __launch_bounds__(512, 2)
void mfma_logits_fused(const half8* __restrict__ hpkA, const half8* __restrict__ Wpk,
                       const float* __restrict__ bd,
                       float* __restrict__ pm, float* __restrict__ ps,
                       float* __restrict__ pt2, float* __restrict__ pbest,
                       float* __restrict__ plb, int* __restrict__ pbi) {
  // ----- XCD-aware bijective swizzle: 2000 = 8 * 250 -----
  const int p = blockIdx.x;
  const int g = (p & 7) * 250 + (p >> 3);
  const int tpair = g & 15;
  const int chunk = g >> 4;

  const int tid = threadIdx.x;
  const int w4 = tid >> 6;      // 0..7
  const int th = w4 >> 2;       // t-half (0/1)
  const int w  = w4 & 3;        // wave within t-half
  const int lane = tid & 63;
  const int lm = lane & 15, q = lane >> 4;
  const int t = tpair * 2 + th;
  const bool active = (t < T_STEPS);
  const int nt0 = chunk * 16 + w * 4;

  floatx4 acc[4][4] = {};

  if (active) {
    const half8* Apk = hpkA + (size_t)(t + 1) * 16384;  // h_{t+1} slot
    half8 a0[4][2], b0[4][2], a1[4][2], b1[4][2];

    LOAD_FRAGS(0, a0, b0);
    for (int s = 0; s < STOT; s += 2) {
      LOAD_FRAGS(s + 1, a1, b1);
      DO_MFMA(a0, b0);
      if (s + 2 < STOT) LOAD_FRAGS(s + 2, a0, b0);
      DO_MFMA(a1, b1);
    }
  }

  // ---------- epilogue: bias + stage-1 partials ----------
  __shared__ float redM[2][4][64];
  __shared__ float redS[2][4][64], redT[2][4][64], redBV[2][4][64], redBL[2][4][64];
  __shared__ int   redBI[2][4][64];

  const int colb = chunk * 256 + w * 64 + lm;
  float M[4][4];

  if (active) {
    float bdv[4];
#pragma unroll
    for (int nt = 0; nt < 4; ++nt) bdv[nt] = bd[colb + nt * 16];
#pragma unroll
    for (int mt = 0; mt < 4; ++mt)
#pragma unroll
      for (int nt = 0; nt < 4; ++nt)
#pragma unroll
        for (int r = 0; r < 4; ++r) acc[mt][nt][r] += bdv[nt];

    // per-row max over this block's 256 cols (in-lane 4, 16-lane xor tree)
#pragma unroll
    for (int mt = 0; mt < 4; ++mt) {
#pragma unroll
      for (int r = 0; r < 4; ++r) {
        float m = fmaxf(fmaxf(acc[mt][0][r], acc[mt][1][r]),
                        fmaxf(acc[mt][2][r], acc[mt][3][r]));
#pragma unroll
        for (int off = 1; off <= 8; off <<= 1) m = fmaxf(m, __shfl_xor(m, off));
        if (lm == 0) redM[th][w][mt * 16 + q * 4 + r] = m;
      }
    }
  }
  __syncthreads();

  if (active) {
#pragma unroll
    for (int mt = 0; mt < 4; ++mt)
#pragma unroll
      for (int r = 0; r < 4; ++r) {
        int b = mt * 16 + q * 4 + r;
        M[mt][r] = fmaxf(fmaxf(redM[th][0][b], redM[th][1][b]),
                         fmaxf(redM[th][2][b], redM[th][3][b]));
      }

    // threefry key for this t (uniform per t-half)
    uint32_t tk0 = 0u, tk1 = (uint32_t)t;
    threefry2x32(0u, 1234u, tk0, tk1);

#pragma unroll
    for (int mt = 0; mt < 4; ++mt) {
#pragma unroll
      for (int r = 0; r < 4; ++r) {
        const int b = mt * 16 + q * 4 + r;
        const float Mrow = M[mt][r];
        float s = 0.f, t2 = 0.f, bv = -INFINITY, bl = 0.f;
        int bi = 0x7fffffff;
#pragma unroll
        for (int nt = 0; nt < 4; ++nt) {
          float l = acc[mt][nt][r];
          int v = colb + nt * 16;
          float e = __expf(l - Mrow);   // fast v_exp: ~1e-7 rel, invisible vs 1.5e-5 GEMM residual
          s += e;
          t2 += e * l;
          uint32_t j = (uint32_t)(b * V_DIM + v);
#if RNG_PARTITIONABLE
          uint32_t y0 = 0u, y1 = j;
          threefry2x32(tk0, tk1, y0, y1);
          uint32_t bits = y0 ^ y1;
#else
          const uint32_t half = (uint32_t)(B_DIM * V_DIM / 2);
          uint32_t y0, y1;
          if (j < half) { y0 = j; y1 = j + half; } else { y0 = j - half; y1 = j; }
          threefry2x32(tk0, tk1, y0, y1);
          uint32_t bits = (j < half) ? y0 : y1;
#endif
          float u = __uint_as_float((bits >> 9) | 0x3f800000u) - 1.0f;
          u = fmaxf(u, 1.17549435e-38f);
          // gumbel steers only the argmax; fast v_log ULP noise is same risk
          // class as XLA-vs-libm differences already present
          float g2 = -__logf(-__logf(u));
          float val = l + g2;
          if (val > bv || (val == bv && v < bi)) { bv = val; bi = v; bl = l; }
        }
        // 16-lane xor reduce (sum / argmax)
#pragma unroll
        for (int off = 1; off <= 8; off <<= 1) {
          s  += __shfl_xor(s, off);
          t2 += __shfl_xor(t2, off);
          float ob = __shfl_xor(bv, off);
          int   oi = __shfl_xor(bi, off);
          float ol = __shfl_xor(bl, off);
          if (ob > bv || (ob == bv && oi < bi)) { bv = ob; bi = oi; bl = ol; }
        }
        if (lm == 0) {
          redS[th][w][b] = s; redT[th][w][b] = t2;
          redBV[th][w][b] = bv; redBI[th][w][b] = bi; redBL[th][w][b] = bl;
        }
      }
    }
  }
  __syncthreads();

  // final cross-wave combine: wave w==0 of each t-half, lane = row b
  if (active && w == 0) {
    int b = lane;
    float Mg = fmaxf(fmaxf(redM[th][0][b], redM[th][1][b]),
                     fmaxf(redM[th][2][b], redM[th][3][b]));
    float S  = redS[th][0][b] + redS[th][1][b] + redS[th][2][b] + redS[th][3][b];
    float T2 = redT[th][0][b] + redT[th][1][b] + redT[th][2][b] + redT[th][3][b];
    float Bv = redBV[th][0][b]; int BI = redBI[th][0][b]; float Bl = redBL[th][0][b];
#pragma unroll
    for (int ww = 1; ww < 4; ++ww) {
      if (redBV[th][ww][b] > Bv || (redBV[th][ww][b] == Bv && redBI[th][ww][b] < BI)) {
        Bv = redBV[th][ww][b]; BI = redBI[th][ww][b]; Bl = redBL[th][ww][b];
      }
    }
    size_t o = ((size_t)t * B_DIM + b) * NCHUNK + chunk;
    pm[o] = Mg; ps[o] = S; pt2[o] = T2; pbest[o] = Bv; plb[o] = Bl;
    pbi[o] = BI;
  }
}
#undef LOAD_FRAGS
#undef DO_MFMA

// ---------------- fp32 GEMM (encoder only, one-shot) ----------------
__global__ __launch_bounds__(256, 2)
void gemm64_kernel(const float* __restrict__ A, const float* __restrict__ W,
                   float* __restrict__ P, int K, int N) {
  const int vt = blockIdx.x;
  const int ks = blockIdx.y;
  const int kchunk = K / gridDim.y;
  const int kbase = ks * kchunk;
  const int v0 = vt * 256;

  __shared__ float As[32][68];
  __shared__ float Ws[32][256];

  float acc[8][8];
#pragma unroll
  for (int i = 0; i < 8; i++)
#pragma unroll
    for (int j = 0; j < 8; j++) acc[i][j] = 0.0f;

  const int tid = threadIdx.x;
  const int cg4 = (tid & 31) * 4;
  const int rg4 = (tid >> 5) * 4;

  for (int k0 = kbase; k0 < kbase + kchunk; k0 += 32) {
    __syncthreads();
    {
      int b  = tid >> 3;
      int f4 = tid & 7;
      const float* Ab = A + (size_t)b * K + k0 + f4 * 4;
      float4 a0 = *(const float4*)Ab;
      float4 a1 = *(const float4*)(Ab + (size_t)32 * K);
      int kk0 = f4 * 4;
      As[kk0+0][b] = a0.x; As[kk0+1][b] = a0.y; As[kk0+2][b] = a0.z; As[kk0+3][b] = a0.w;
      As[kk0+0][b+32] = a1.x; As[kk0+1][b+32] = a1.y; As[kk0+2][b+32] = a1.z; As[kk0+3][b+32] = a1.w;
    }
#pragma unroll
    for (int p = 0; p < 8; p++) {
      int idx = tid + p * 256;
      int row = idx >> 6, c4 = idx & 63;
      *(float4*)&Ws[row][c4 * 4] =
          *(const float4*)(W + (size_t)(k0 + row) * N + v0 + c4 * 4);
    }
    __syncthreads();

#pragma unroll 8
    for (int kk = 0; kk < 32; kk++) {
      float4 a0 = *(const float4*)&As[kk][rg4];
      float4 a1 = *(const float4*)&As[kk][32 + rg4];
      float4 w0 = *(const float4*)&Ws[kk][cg4];
      float4 w1 = *(const float4*)&Ws[kk][128 + cg4];
      float av[8] = {a0.x, a0.y, a0.z, a0.w, a1.x, a1.y, a1.z, a1.w};
      float wv[8] = {w0.x, w0.y, w0.z, w0.w, w1.x, w1.y, w1.z, w1.w};
#pragma unroll
      for (int i = 0; i < 8; i++)
#pragma unroll
        for (int j = 0; j < 8; j++)
          acc[i][j] = fmaf(av[i], wv[j], acc[i][j]);
    }
  }

  const size_t base = (size_t)ks * 64 * N;
#pragma unroll
  for (int i = 0; i < 8; i++) {
    int row = (i < 4) ? (rg4 + i) : (32 + rg4 + i - 4);
    float4 s0 = make_float4(acc[i][0], acc[i][1], acc[i][2], acc[i][3]);
    float4 s1 = make_float4(acc[i][4], acc[i][5], acc[i][6], acc[i][7]);
    *(float4*)(P + base + (size_t)row * N + v0 + cg4) = s0;
    *(float4*)(P + base + (size_t)row * N + v0 + 128 + cg4) = s1;
  }
}

// ---------------- LSTM gate fusion + A-fragment pack (encoder only) ------------
__global__ void gates_kernel(const float* __restrict__ zp, int ksplit,
                             const float* __restrict__ bias,
                             const float* __restrict__ c_in,
                             float* __restrict__ h_out, float* __restrict__ c_out,
                             _Float16* __restrict__ hpk) {
  int tid = blockIdx.x * blockDim.x + threadIdx.x;
  if (tid >= B_DIM * H_DIM) return;
  int b = tid >> 10, j = tid & 1023;
  float zi = bias[j], zf = bias[j + 1024], zg = bias[j + 2048], zo = bias[j + 3072];
  const float* Pb = zp + (size_t)b * GATES;
  for (int p = 0; p < ksplit; p++) {
    const float* P = Pb + (size_t)p * B_DIM * GATES;
    zi += P[j]; zf += P[j + 1024]; zg += P[j + 2048]; zo += P[j + 3072];
  }
  float cp = c_in ? c_in[tid] : 0.0f;
  float si = 1.0f / (1.0f + expf(-zi));
  float sf = 1.0f / (1.0f + expf(-zf));
  float so = 1.0f / (1.0f + expf(-zo));
  float c = sf * cp + si * zg;
  c_out[tid] = c;
  float hv = so * c;
  h_out[tid] = hv;

  int mt = b >> 4, lm = b & 15;
  int s = j >> 5, quad = (j >> 3) & 3, jj = j & 7;
  size_t off = ((size_t)(mt * 32 + s) * 2) * 512 + (size_t)(quad * 16 + lm) * 8 + jj;
  _Float16 hh = (_Float16)hv;
  hpk[off] = hh;
  hpk[off + 512] = (_Float16)(hv - (float)hh);
}

// ---------------- batched sampling stage 2: reduce 125 chunks per (b,t) ---------
__global__ __launch_bounds__(128)
void sample_stage2_batch(const float* __restrict__ pm, const float* __restrict__ ps,
                         const float* __restrict__ pt2, const float* __restrict__ pbest,
                         const float* __restrict__ plb, const int* __restrict__ pbi,
                         float* __restrict__ out) {
  const int b = blockIdx.x;
  const int t = blockIdx.y;
  const int tid = threadIdx.x;
  const size_t base = ((size_t)t * B_DIM + b) * NCHUNK;
  const bool valid = tid < NCHUNK;

  float m   = valid ? pm[base + tid]    : -INFINITY;
  float bv  = valid ? pbest[base + tid] : -INFINITY;
  float blv = valid ? plb[base + tid]   : 0.0f;
  int   bi  = valid ? pbi[base + tid]   : 0x7fffffff;

  float M = m;
  for (int off = 32; off > 0; off >>= 1) M = fmaxf(M, __shfl_down(M, off));
  __shared__ float sM[2];
  int wave = tid >> 6, lane = tid & 63;
  if (lane == 0) sM[wave] = M;
  __syncthreads();
  const float Mg = fmaxf(sM[0], sM[1]);

  float sc = valid ? expf(m - Mg) : 0.0f;
  float s  = valid ? ps[base + tid]  * sc : 0.0f;
  float t2 = valid ? pt2[base + tid] * sc : 0.0f;
  for (int off = 32; off > 0; off >>= 1) {
    s  += __shfl_down(s, off);
    t2 += __shfl_down(t2, off);
    float ob = __shfl_down(bv, off);
    int   oi = __shfl_down(bi, off);
    float ol = __shfl_down(blv, off);
    if (ob > bv || (ob == bv && oi < bi)) { bv = ob; bi = oi; blv = ol; }
  }
  __shared__ float sS[2], sT[2], sB[2], sL[2];
  __shared__ int sI[2];
  if (lane == 0) { sS[wave] = s; sT[wave] = t2; sB[wave] = bv; sI[wave] = bi; sL[wave] = blv; }
  __syncthreads();
  if (tid == 0) {
    float S = sS[0] + sS[1], T2 = sT[0] + sT[1];
    float Bv = sB[0], Bl = sL[0]; int BI = sI[0];
    if (sB[1] > Bv || (sB[1] == Bv && sI[1] < BI)) { Bv = sB[1]; BI = sI[1]; Bl = sL[1]; }
    float lse = Mg + logf(S);
    out[(size_t)b * OUT_COLS + t]        = (float)BI;    // msg
    out[3968 + (size_t)b * OUT_COLS + t] = Bl - lse;     // log_prob
    out[7936 + (size_t)b * OUT_COLS + t] = lse - T2 / S; // entropy
  }
}

// ---------------- launcher ----------------
extern "C" void kernel_launch(void* const* d_in, const int* in_sizes, int n_in,
                              void* d_out, int out_size, void* d_ws, size_t ws_size,
                              hipStream_t stream) {
  const float* inp = (const float*)d_in[0];
  const float* Wx1 = (const float*)d_in[1];
  // d_in[2] = Wh1: unused (encoder initial h == 0)
  const float* b1  = (const float*)d_in[3];
  const float* Wx2 = (const float*)d_in[4];
  const float* Wh2 = (const float*)d_in[5];
  const float* b2  = (const float*)d_in[6];
  const float* Wd  = (const float*)d_in[7];
  const float* bd  = (const float*)d_in[8];
  float* out = (float*)d_out;

  float* ws = (float*)d_ws;
  float* Wd_pk  = ws;                    // 32,768,000 floats (131 MB f16 hi/lo)
  float* W2_pk  = Wd_pk + 32768000;      //  4,194,304
  float* hpkA   = W2_pk + 4194304;       //  2,097,152 (32 slots x 65,536: h_0..h_31 packed)
  float* zparts = hpkA + 2097152;        //  2,097,152 (encoder k-split parts; partials alias)
  float* h      = zparts + 2097152;      //     65,536
  float* c      = h + 65536;             //     65,536

  // sampling partials alias zparts (dead after the encoder phase)
  float* pm    = zparts;
  float* ps    = zparts + 248000;
  float* pt2   = zparts + 496000;
  float* pbest = zparts + 744000;
  float* plb   = zparts + 992000;
  int*   pbi   = (int*)(zparts + 1240000);

  // one-time: repack Wd and (Wx2+Wh2) into f16 hi/lo MFMA fragments
  repack_w<<<16000, 256, 0, stream>>>(Wd, nullptr, (_Float16*)Wd_pk, V_DIM);
  repack_w<<<2048, 256, 0, stream>>>(Wx2, Wh2, (_Float16*)W2_pk, GATES);
  zero_kernel<<<47, 256, 0, stream>>>(out, 11904);

  // encoder: single step, zero initial state -> z = x@Wx1 + b1 (fp32, one-shot)
  gemm64_kernel<<<dim3(16, 4), 256, 0, stream>>>(inp, Wx1, zparts, E_DIM, GATES);
  gates_kernel<<<256, 256, 0, stream>>>(zparts, 4, b1, nullptr, h, c,
                                        (_Float16*)hpkA);  // slot 0 = h_0

  // Phase A: state recurrence, ONE fused kernel per step (no z round-trip,
  // no separate gates launch). Slots 1..31.
  for (int t = 0; t < T_STEPS; t++) {
    lstm_step_fused<<<dim3(64, 2), 512, 0, stream>>>(
        (const half8*)(hpkA + (size_t)t * 65536), (const half8*)W2_pk,
        b2, c, h, (_Float16*)(hpkA + (size_t)(t + 1) * 65536));
  }

  // Phase B: ONE fused dispatch for all 31 logits GEMMs + sampling stage 1.
  // 512-thread t-paired blocks, XCD-swizzled inside the kernel.
  mfma_logits_fused<<<dim3(NBLK2), 512, 0, stream>>>(
      (const half8*)hpkA, (const half8*)Wd_pk, bd,
      pm, ps, pt2, pbest, plb, pbi);

  // Phase C: one batched stage-2 reduction for all (b, t)
  sample_stage2_batch<<<dim3(B_DIM, T_STEPS), 128, 0, stream>>>(
      pm, ps, pt2, pbest, plb, pbi, out);

  copy_kernel<<<256, 256, 0, stream>>>(h, out + 11904, B_DIM * H_DIM);
}